// Round 5
// baseline (571.614 us; speedup 1.0000x reference)
//
#include <hip/hip_runtime.h>
#include <math.h>

#define DX 192
#define DY 192
#define DZ 128
#define DB 4
#define DXY (DX*DY)          // 36864
#define NTOT (DB*DZ*DXY)     // 18874368
#define XV (DX/4)            // 48 vec4 groups per row
#define NCOL (DB*DZ*XV)      // 24576 columns (b,z,xv4)
#define SEG 12               // y rows per thread
#define NSEG (DY/SEG)        // 16 segments per column

// ws layout (doubles): [0..12] sum(di*dt), [13..25] sum(dt*dt), [26] bce sum

__device__ inline float wred(float v) {
    #pragma unroll
    for (int o = 32; o > 0; o >>= 1) v += __shfl_down(v, o, 64);
    return v;
}

__device__ inline float4 ld4(const float* p) { return *(const float4*)p; }

// --- term macros -----------------------------------------------------------
#define TN(k, A1, A0, D1, D0) do { float di_=(A1)-(A0); float dt_=(D1)-(D0); \
    sk[k] += di_*dt_; rk[k] += dt_*dt_; } while(0)
#define TM(k, A1, A0, D1, D0) do { float di_=(A1)-(A0); float dt_=(D1)-(D0); \
    float dm_=fx3*dt_; sk[k] += di_*dm_; rk[k] += dt_*dm_; } while(0)
#define BCEACC(A0, D0) do { bces += (D0)*__logf(A0) + (1.0f-(D0))*__logf(1.0f-(A0)); } while(0)

// corners (z,y,x): a0=(0,0,0) a1=(0,0,1) a2=(0,1,0) a3=(0,1,1)
//                  a4=(1,0,0) a5=(1,0,1) a6=(1,1,0) a7=(1,1,1)
// offsets -> pairs: k0:(4,0) k1:(2,0) k2:(1,0) k3:(6,0) k4:(4,2) k5:(3,0)
//                   k6:(2,1) k7:(4,1) k8:(5,0) k9:(4,3) k10:(6,1) k11:(7,0) k12:(5,2)

#define ELEM_FULL(a0,a1,a2,a3,a4,a5,a6,a7, d0,d1,d2,d3,d4,d5,d6,d7) do { \
    TN(0,a4,a0,d4,d0); TN(1,a2,a0,d2,d0); TN(2,a1,a0,d1,d0); TN(3,a6,a0,d6,d0); \
    TN(4,a4,a2,d4,d2); TN(5,a3,a0,d3,d0); TN(6,a2,a1,d2,d1); TN(7,a4,a1,d4,d1); \
    TN(8,a5,a0,d5,d0); TN(9,a4,a3,d4,d3); TN(10,a6,a1,d6,d1); TN(11,a7,a0,d7,d0); \
    TN(12,a5,a2,d5,d2); BCEACC(a0,d0); } while(0)

#define ELEM_FX(a0,a1,a2,a3,a4,a5,a6,a7, d0,d1,d2,d3,d4,d5,d6,d7) do { \
    TN(0,a4,a0,d4,d0); TN(1,a2,a0,d2,d0); TM(2,a1,a0,d1,d0); TN(3,a6,a0,d6,d0); \
    TN(4,a4,a2,d4,d2); TM(5,a3,a0,d3,d0); TM(6,a2,a1,d2,d1); TM(7,a4,a1,d4,d1); \
    TM(8,a5,a0,d5,d0); TM(9,a4,a3,d4,d3); TM(10,a6,a1,d6,d1); TM(11,a7,a0,d7,d0); \
    TM(12,a5,a2,d5,d2); BCEACC(a0,d0); } while(0)

// y=191 peel (z<127): only dy==0 offsets survive: k0,k2,k7,k8
#define PEL_FULL(a0,a1,a4,a5, d0,d1,d4,d5) do { \
    TN(0,a4,a0,d4,d0); TN(2,a1,a0,d1,d0); TN(7,a4,a1,d4,d1); TN(8,a5,a0,d5,d0); \
    BCEACC(a0,d0); } while(0)
#define PEL_FX(a0,a1,a4,a5, d0,d1,d4,d5) do { \
    TN(0,a4,a0,d4,d0); TM(2,a1,a0,d1,d0); TM(7,a4,a1,d4,d1); TM(8,a5,a0,d5,d0); \
    BCEACC(a0,d0); } while(0)

// z=127 body: only dz==0 offsets survive: k1,k2,k5,k6
#define ZEL_FULL(a0,a1,a2,a3, d0,d1,d2,d3) do { \
    TN(1,a2,a0,d2,d0); TN(2,a1,a0,d1,d0); TN(5,a3,a0,d3,d0); TN(6,a2,a1,d2,d1); \
    BCEACC(a0,d0); } while(0)
#define ZEL_FX(a0,a1,a2,a3, d0,d1,d2,d3) do { \
    TN(1,a2,a0,d2,d0); TM(2,a1,a0,d1,d0); TM(5,a3,a0,d3,d0); TM(6,a2,a1,d2,d1); \
    BCEACC(a0,d0); } while(0)

// z=127, y=191 peel: only k2
#define ZPEL_FULL(a0,a1, d0,d1) do { TN(2,a1,a0,d1,d0); BCEACC(a0,d0); } while(0)
#define ZPEL_FX(a0,a1, d0,d1)   do { TM(2,a1,a0,d1,d0); BCEACC(a0,d0); } while(0)

// --- register-set machinery: 4 named sets, modulo-renamed (no rotate movs) --
#define DECLSET(S) float4 S##i0, S##i1, S##t0, S##t1; \
                   float  S##ie, S##iz, S##te, S##tz;

// int-offset addressing off uniform bases -> saddr-form loads, 4 addr VGPRs
#define LOADSET(S, k) do { \
    S##i0 = ld4(inp + off  + (k)*DX); S##i1 = ld4(inp + offz + (k)*DX); \
    S##t0 = ld4(tgt + off  + (k)*DX); S##t1 = ld4(tgt + offz + (k)*DX); \
    S##ie = inp[offe  + (k)*DX];      S##iz = inp[offze + (k)*DX]; \
    S##te = tgt[offe  + (k)*DX];      S##tz = tgt[offze + (k)*DX]; } while(0)

#define COMP(A,B) do { \
    ELEM_FULL(A##i0.x,A##i0.y, B##i0.x,B##i0.y, A##i1.x,A##i1.y, B##i1.x,B##i1.y, \
              A##t0.x,A##t0.y, B##t0.x,B##t0.y, A##t1.x,A##t1.y, B##t1.x,B##t1.y); \
    ELEM_FULL(A##i0.y,A##i0.z, B##i0.y,B##i0.z, A##i1.y,A##i1.z, B##i1.y,B##i1.z, \
              A##t0.y,A##t0.z, B##t0.y,B##t0.z, A##t1.y,A##t1.z, B##t1.y,B##t1.z); \
    ELEM_FULL(A##i0.z,A##i0.w, B##i0.z,B##i0.w, A##i1.z,A##i1.w, B##i1.z,B##i1.w, \
              A##t0.z,A##t0.w, B##t0.z,B##t0.w, A##t1.z,A##t1.w, B##t1.z,B##t1.w); \
    ELEM_FX  (A##i0.w,A##ie,  B##i0.w,B##ie,  A##i1.w,A##iz,  B##i1.w,B##iz, \
              A##t0.w,A##te,  B##t0.w,B##te,  A##t1.w,A##tz,  B##t1.w,B##tz); \
    } while(0)

#define PEELSET(S) do { \
    PEL_FULL(S##i0.x,S##i0.y, S##i1.x,S##i1.y, S##t0.x,S##t0.y, S##t1.x,S##t1.y); \
    PEL_FULL(S##i0.y,S##i0.z, S##i1.y,S##i1.z, S##t0.y,S##t0.z, S##t1.y,S##t1.z); \
    PEL_FULL(S##i0.z,S##i0.w, S##i1.z,S##i1.w, S##t0.z,S##t0.w, S##t1.z,S##t1.w); \
    PEL_FX  (S##i0.w,S##ie,  S##i1.w,S##iz,  S##t0.w,S##te,  S##t1.w,S##tz); \
    } while(0)

#define ZCOMP(A,B) do { \
    ZEL_FULL(A##i0.x,A##i0.y, B##i0.x,B##i0.y, A##t0.x,A##t0.y, B##t0.x,B##t0.y); \
    ZEL_FULL(A##i0.y,A##i0.z, B##i0.y,B##i0.z, A##t0.y,A##t0.z, B##t0.y,B##t0.z); \
    ZEL_FULL(A##i0.z,A##i0.w, B##i0.z,B##i0.w, A##t0.z,A##t0.w, B##t0.z,B##t0.w); \
    ZEL_FX  (A##i0.w,A##ie,  B##i0.w,B##ie,  A##t0.w,A##te,  B##t0.w,B##te); \
    } while(0)

__global__ __launch_bounds__(256, 4) void gc3d_main(const float* __restrict__ inp,
                                                    const float* __restrict__ tgt,
                                                    double* __restrict__ acc) {
    float sk[13] = {0,0,0,0,0,0,0,0,0,0,0,0,0};
    float rk[13] = {0,0,0,0,0,0,0,0,0,0,0,0,0};
    float bces = 0.f;

    int c   = blockIdx.x * 256 + threadIdx.x;   // [0, 24576)
    int s   = blockIdx.y;                       // [0, 16)
    int xv4 = c % XV;
    int zb  = c / XV;                           // b*DZ + z, [0, 512)
    int z   = zb & (DZ - 1);
    int y0  = s * SEG;
    bool xlast = (xv4 == XV - 1);
    int   xe   = xlast ? 3 : 4;
    float fx3  = xlast ? 0.f : 1.f;
    bool lastseg = (s == NSEG - 1);
    int  nfull   = SEG - (lastseg ? 1 : 0);     // 12, or 11 on last segment

    int off  = (zb * DY + y0) * DX + xv4 * 4;   // 32-bit elem offset (fits: 75M)
    int offe = off + xe;
    int offz = off + DXY;
    int offze = offz + xe;

    if (z != DZ - 1) {
        // ---------- z-interior: modulo-4 renamed software pipeline ----------
        DECLSET(A) DECLSET(B) DECLSET(C) DECLSET(D)
        LOADSET(A, 0); LOADSET(B, 1); LOADSET(C, 2);

        // 2 iterations for both nfull=12 and nfull=11; computes pairs (0,1)..(7,8)
        for (int r = 0; r + 6 <= nfull; r += 4) {
            LOADSET(D, 3); COMP(A, B);
            LOADSET(A, 4); COMP(B, C);
            LOADSET(B, 5); COMP(C, D);
            LOADSET(C, 6); COMP(D, A);
            off += 4 * DX; offz += 4 * DX; offe += 4 * DX; offze += 4 * DX;
        }
        // state: A=row8, B=row9, C=row10 (off at row8 base)
        LOADSET(D, 3);           // row 11
        COMP(A, B);              // (8,9)
        if (!lastseg) {
            LOADSET(A, 4);       // row 12 (= y0+12 <= 180, valid)
            COMP(B, C);          // (9,10)
            COMP(C, D);          // (10,11)
            COMP(D, A);          // (11,12)
        } else {
            COMP(B, C);          // (9,10)
            COMP(C, D);          // (10,11)  -- row 11 = y 191
            PEELSET(D);          // y = 191 edge terms
        }
    } else {
        // ---------- z = 127 path (1/128 of columns): rolled dist-1 pipeline ----------
        float4 Pi0 = ld4(inp + off),      Pt0 = ld4(tgt + off);
        float  Pie = inp[offe],           Pte = tgt[offe];
        float4 Qi0 = ld4(inp + off + DX), Qt0 = ld4(tgt + off + DX);
        float  Qie = inp[offe + DX],      Qte = tgt[offe + DX];

        #pragma unroll 2
        for (int it = 0; it < nfull - 1; ++it) {
            float4 Ri0 = ld4(inp + off + 2*DX), Rt0 = ld4(tgt + off + 2*DX);
            float  Rie = inp[offe + 2*DX],      Rte = tgt[offe + 2*DX];

            ZCOMP(P, Q);

            Pi0 = Qi0; Pt0 = Qt0; Pie = Qie; Pte = Qte;
            Qi0 = Ri0; Qt0 = Rt0; Qie = Rie; Qte = Rte;
            off += DX; offe += DX;
        }
        ZCOMP(P, Q);
        if (lastseg) {
            ZPEL_FULL(Qi0.x,Qi0.y, Qt0.x,Qt0.y);
            ZPEL_FULL(Qi0.y,Qi0.z, Qt0.y,Qt0.z);
            ZPEL_FULL(Qi0.z,Qi0.w, Qt0.z,Qt0.w);
            ZPEL_FX  (Qi0.w,Qie,  Qt0.w,Qte);
        }
    }

    // block reduction: wave shuffle -> LDS -> 27 double atomics
    float vals[27];
    #pragma unroll
    for (int q = 0; q < 13; q++) { vals[q] = sk[q]; vals[13 + q] = rk[q]; }
    vals[26] = bces;
    #pragma unroll
    for (int q = 0; q < 27; q++) vals[q] = wred(vals[q]);

    __shared__ float red[4][27];
    int lane = threadIdx.x & 63;
    int wave = threadIdx.x >> 6;
    if (lane == 0) {
        #pragma unroll
        for (int q = 0; q < 27; q++) red[wave][q] = vals[q];
    }
    __syncthreads();
    if (threadIdx.x < 27) {
        float t = red[0][threadIdx.x] + red[1][threadIdx.x]
                + red[2][threadIdx.x] + red[3][threadIdx.x];
        atomicAdd(&acc[threadIdx.x], (double)t);
    }
}

__global__ void gc3d_final(const double* __restrict__ acc, float* __restrict__ out) {
    if (threadIdx.x == 0 && blockIdx.x == 0) {
        double s = 0.0;
        #pragma unroll
        for (int k = 0; k < 13; k++) s += acc[k] / (acc[13 + k] + 1e-5);
        double bce = -acc[26] / (double)NTOT;
        out[0] = (float)(bce + 1.0 - s / 13.0);
    }
}

extern "C" void kernel_launch(void* const* d_in, const int* in_sizes, int n_in,
                              void* d_out, int out_size, void* d_ws, size_t ws_size,
                              hipStream_t stream) {
    const float* inp = (const float*)d_in[0];
    const float* tgt = (const float*)d_in[1];
    double* acc = (double*)d_ws;

    hipMemsetAsync(d_ws, 0, 27 * sizeof(double), stream);
    dim3 grid(NCOL / 256, NSEG);
    gc3d_main<<<grid, 256, 0, stream>>>(inp, tgt, acc);
    gc3d_final<<<1, 64, 0, stream>>>(acc, (float*)d_out);
}

// Round 6
// 244.192 us; speedup vs baseline: 2.3408x; 2.3408x over previous
//
#include <hip/hip_runtime.h>
#include <math.h>

#define DX 192
#define DY 192
#define DZ 128
#define DB 4
#define DXY (DX*DY)          // 36864
#define NTOT (DB*DZ*DXY)     // 18874368
#define SEG 8                // y rows per wave-job
#define NSEG (DY/SEG)        // 24 segments per strip
#define NSTRIP (DB*DZ)       // 512 strips (b,z)

// ws layout (doubles): [0..12] sum(di*dt), [13..25] sum(dt*dt), [26] bce sum

__device__ inline float wred(float v) {
    #pragma unroll
    for (int o = 32; o > 0; o >>= 1) v += __shfl_down(v, o, 64);
    return v;
}

struct f3 { float x, y, z; };
__device__ inline f3 ld3(const float* p) { return *(const f3*)p; }
__device__ inline float shfl1(float v) { return __shfl_down(v, 1, 64); }

// --- term macros -----------------------------------------------------------
#define TN(k, A1, A0, D1, D0) do { float di_=(A1)-(A0); float dt_=(D1)-(D0); \
    sk[k] += di_*dt_; rk[k] += dt_*dt_; } while(0)
#define TM(k, A1, A0, D1, D0) do { float di_=(A1)-(A0); float dt_=(D1)-(D0); \
    float dm_=fx3*dt_; sk[k] += di_*dm_; rk[k] += dt_*dm_; } while(0)
#define BCEACC(A0, D0) do { bces += (D0)*__logf(A0) + (1.0f-(D0))*__logf(1.0f-(A0)); } while(0)

// corners (z,y,x): a0=(0,0,0) a1=(0,0,1) a2=(0,1,0) a3=(0,1,1)
//                  a4=(1,0,0) a5=(1,0,1) a6=(1,1,0) a7=(1,1,1)
// offsets -> pairs: k0:(4,0) k1:(2,0) k2:(1,0) k3:(6,0) k4:(4,2) k5:(3,0)
//                   k6:(2,1) k7:(4,1) k8:(5,0) k9:(4,3) k10:(6,1) k11:(7,0) k12:(5,2)

#define ELEM_FULL(a0,a1,a2,a3,a4,a5,a6,a7, d0,d1,d2,d3,d4,d5,d6,d7) do { \
    TN(0,a4,a0,d4,d0); TN(1,a2,a0,d2,d0); TN(2,a1,a0,d1,d0); TN(3,a6,a0,d6,d0); \
    TN(4,a4,a2,d4,d2); TN(5,a3,a0,d3,d0); TN(6,a2,a1,d2,d1); TN(7,a4,a1,d4,d1); \
    TN(8,a5,a0,d5,d0); TN(9,a4,a3,d4,d3); TN(10,a6,a1,d6,d1); TN(11,a7,a0,d7,d0); \
    TN(12,a5,a2,d5,d2); BCEACC(a0,d0); } while(0)

#define ELEM_FX(a0,a1,a2,a3,a4,a5,a6,a7, d0,d1,d2,d3,d4,d5,d6,d7) do { \
    TN(0,a4,a0,d4,d0); TN(1,a2,a0,d2,d0); TM(2,a1,a0,d1,d0); TN(3,a6,a0,d6,d0); \
    TN(4,a4,a2,d4,d2); TM(5,a3,a0,d3,d0); TM(6,a2,a1,d2,d1); TM(7,a4,a1,d4,d1); \
    TM(8,a5,a0,d5,d0); TM(9,a4,a3,d4,d3); TM(10,a6,a1,d6,d1); TM(11,a7,a0,d7,d0); \
    TM(12,a5,a2,d5,d2); BCEACC(a0,d0); } while(0)

// y=191 peel (z<127): only dy==0 offsets: k0,k2,k7,k8
#define PEL_FULL(a0,a1,a4,a5, d0,d1,d4,d5) do { \
    TN(0,a4,a0,d4,d0); TN(2,a1,a0,d1,d0); TN(7,a4,a1,d4,d1); TN(8,a5,a0,d5,d0); \
    BCEACC(a0,d0); } while(0)
#define PEL_FX(a0,a1,a4,a5, d0,d1,d4,d5) do { \
    TN(0,a4,a0,d4,d0); TM(2,a1,a0,d1,d0); TM(7,a4,a1,d4,d1); TM(8,a5,a0,d5,d0); \
    BCEACC(a0,d0); } while(0)

// z=127 body: only dz==0 offsets: k1,k2,k5,k6
#define ZEL_FULL(a0,a1,a2,a3, d0,d1,d2,d3) do { \
    TN(1,a2,a0,d2,d0); TN(2,a1,a0,d1,d0); TN(5,a3,a0,d3,d0); TN(6,a2,a1,d2,d1); \
    BCEACC(a0,d0); } while(0)
#define ZEL_FX(a0,a1,a2,a3, d0,d1,d2,d3) do { \
    TN(1,a2,a0,d2,d0); TM(2,a1,a0,d1,d0); TM(5,a3,a0,d3,d0); TM(6,a2,a1,d2,d1); \
    BCEACC(a0,d0); } while(0)

// z=127, y=191 peel: only k2
#define ZPEL_FULL(a0,a1, d0,d1) do { TN(2,a1,a0,d1,d0); BCEACC(a0,d0); } while(0)
#define ZPEL_FX(a0,a1, d0,d1)   do { TM(2,a1,a0,d1,d0); BCEACC(a0,d0); } while(0)

// --- row-set machinery: sets of 4 f3 (i@z, i@z+1, t@z, t@z+1) --------------
#define DECLSET(S)  f3 S##i0, S##i1, S##t0, S##t1;
#define LOADSET(S, k) do { \
    S##i0 = ld3(inp + off  + (k)*DX); S##i1 = ld3(inp + offz + (k)*DX); \
    S##t0 = ld3(tgt + off  + (k)*DX); S##t1 = ld3(tgt + offz + (k)*DX); } while(0)

// compute row at set A (y) with set B (y+1); 3 elements per lane
#define COMP(A,B) do { \
    float Ae0 = shfl1(A##i0.x), Be0 = shfl1(B##i0.x); \
    float Ae1 = shfl1(A##i1.x), Be1 = shfl1(B##i1.x); \
    float Af0 = shfl1(A##t0.x), Bf0 = shfl1(B##t0.x); \
    float Af1 = shfl1(A##t1.x), Bf1 = shfl1(B##t1.x); \
    ELEM_FULL(A##i0.x,A##i0.y, B##i0.x,B##i0.y, A##i1.x,A##i1.y, B##i1.x,B##i1.y, \
              A##t0.x,A##t0.y, B##t0.x,B##t0.y, A##t1.x,A##t1.y, B##t1.x,B##t1.y); \
    ELEM_FULL(A##i0.y,A##i0.z, B##i0.y,B##i0.z, A##i1.y,A##i1.z, B##i1.y,B##i1.z, \
              A##t0.y,A##t0.z, B##t0.y,B##t0.z, A##t1.y,A##t1.z, B##t1.y,B##t1.z); \
    ELEM_FX  (A##i0.z,Ae0,     B##i0.z,Be0,     A##i1.z,Ae1,     B##i1.z,Be1, \
              A##t0.z,Af0,     B##t0.z,Bf0,     A##t1.z,Af1,     B##t1.z,Bf1); \
    } while(0)

#define PEELSET(S) do { \
    float Se0 = shfl1(S##i0.x), Se1 = shfl1(S##i1.x); \
    float Sf0 = shfl1(S##t0.x), Sf1 = shfl1(S##t1.x); \
    PEL_FULL(S##i0.x,S##i0.y, S##i1.x,S##i1.y, S##t0.x,S##t0.y, S##t1.x,S##t1.y); \
    PEL_FULL(S##i0.y,S##i0.z, S##i1.y,S##i1.z, S##t0.y,S##t0.z, S##t1.y,S##t1.z); \
    PEL_FX  (S##i0.z,Se0,     S##i1.z,Se1,     S##t0.z,Sf0,     S##t1.z,Sf1); \
    } while(0)

#define ZDECLSET(S)  f3 S##i0, S##t0;
#define ZLOADSET(S, k) do { \
    S##i0 = ld3(inp + off + (k)*DX); S##t0 = ld3(tgt + off + (k)*DX); } while(0)

#define ZCOMP(A,B) do { \
    float Ae0 = shfl1(A##i0.x), Be0 = shfl1(B##i0.x); \
    float Af0 = shfl1(A##t0.x), Bf0 = shfl1(B##t0.x); \
    ZEL_FULL(A##i0.x,A##i0.y, B##i0.x,B##i0.y, A##t0.x,A##t0.y, B##t0.x,B##t0.y); \
    ZEL_FULL(A##i0.y,A##i0.z, B##i0.y,B##i0.z, A##t0.y,A##t0.z, B##t0.y,B##t0.z); \
    ZEL_FX  (A##i0.z,Ae0,     B##i0.z,Be0,     A##t0.z,Af0,     B##t0.z,Bf0); \
    } while(0)

#define ZPEELSET(S) do { \
    float Se0 = shfl1(S##i0.x), Sf0 = shfl1(S##t0.x); \
    ZPEL_FULL(S##i0.x,S##i0.y, S##t0.x,S##t0.y); \
    ZPEL_FULL(S##i0.y,S##i0.z, S##t0.y,S##t0.z); \
    ZPEL_FX  (S##i0.z,Se0,     S##t0.z,Sf0); \
    } while(0)

__global__ __launch_bounds__(256) void gc3d_main(const float* __restrict__ inp,
                                                 const float* __restrict__ tgt,
                                                 double* __restrict__ acc) {
    float sk[13] = {0,0,0,0,0,0,0,0,0,0,0,0,0};
    float rk[13] = {0,0,0,0,0,0,0,0,0,0,0,0,0};
    float bces = 0.f;

    // grid: (NSEG/4, NSTRIP). wave w of a block handles segment blockIdx.x*4+w
    // of strip blockIdx.y. Each wave = one (b,z) row set; lane covers x=3*lane..3*lane+2.
    int lane = threadIdx.x & 63;
    int wave = threadIdx.x >> 6;
    int seg  = blockIdx.x * 4 + wave;           // [0, 24)
    int zb   = blockIdx.y;                      // [0, 512)
    int z    = zb & (DZ - 1);
    int y0   = seg * SEG;
    bool lastseg = (seg == NSEG - 1);
    float fx3 = (lane == 63) ? 0.f : 1.f;       // x-validity of lane elem 2

    int off  = (zb * DY + y0) * DX + lane * 3;  // 32-bit elem offset
    int offz = off + DXY;

    if (z != DZ - 1) {
        // ---------- z-interior: fully-unrolled modulo-3 pipeline ----------
        DECLSET(A) DECLSET(B) DECLSET(C)
        LOADSET(A, 0); LOADSET(B, 1);
        if (!lastseg) {
            // rows y0..y0+8 (row y0+8 <= 184 always valid), 8 comps
            LOADSET(C, 2); COMP(A, B);     // (0,1)
            LOADSET(A, 3); COMP(B, C);     // (1,2)
            LOADSET(B, 4); COMP(C, A);     // (2,3)
            LOADSET(C, 5); COMP(A, B);     // (3,4)
            LOADSET(A, 6); COMP(B, C);     // (4,5)
            LOADSET(B, 7); COMP(C, A);     // (5,6)
            LOADSET(C, 8); COMP(A, B);     // (6,7)
            COMP(B, C);                    // (7,8)
        } else {
            // rows 184..191: 7 comps + y=191 peel
            LOADSET(C, 2); COMP(A, B);     // (0,1)
            LOADSET(A, 3); COMP(B, C);     // (1,2)
            LOADSET(B, 4); COMP(C, A);     // (2,3)
            LOADSET(C, 5); COMP(A, B);     // (3,4)
            LOADSET(A, 6); COMP(B, C);     // (4,5)
            LOADSET(B, 7); COMP(C, A);     // (5,6)
            COMP(A, B);                    // (6,7)
            PEELSET(B);                    // row 7 = y191
        }
    } else {
        // ---------- z = 127 strips (4 of 512): no z+1 corners ----------
        ZDECLSET(A) ZDECLSET(B) ZDECLSET(C)
        ZLOADSET(A, 0); ZLOADSET(B, 1);
        if (!lastseg) {
            ZLOADSET(C, 2); ZCOMP(A, B);
            ZLOADSET(A, 3); ZCOMP(B, C);
            ZLOADSET(B, 4); ZCOMP(C, A);
            ZLOADSET(C, 5); ZCOMP(A, B);
            ZLOADSET(A, 6); ZCOMP(B, C);
            ZLOADSET(B, 7); ZCOMP(C, A);
            ZLOADSET(C, 8); ZCOMP(A, B);
            ZCOMP(B, C);
        } else {
            ZLOADSET(C, 2); ZCOMP(A, B);
            ZLOADSET(A, 3); ZCOMP(B, C);
            ZLOADSET(B, 4); ZCOMP(C, A);
            ZLOADSET(C, 5); ZCOMP(A, B);
            ZLOADSET(A, 6); ZCOMP(B, C);
            ZLOADSET(B, 7); ZCOMP(C, A);
            ZCOMP(A, B);
            ZPEELSET(B);
        }
    }

    // block reduction: wave shuffle -> LDS -> 27 double atomics
    float vals[27];
    #pragma unroll
    for (int q = 0; q < 13; q++) { vals[q] = sk[q]; vals[13 + q] = rk[q]; }
    vals[26] = bces;
    #pragma unroll
    for (int q = 0; q < 27; q++) vals[q] = wred(vals[q]);

    __shared__ float red[4][27];
    if (lane == 0) {
        #pragma unroll
        for (int q = 0; q < 27; q++) red[wave][q] = vals[q];
    }
    __syncthreads();
    if (threadIdx.x < 27) {
        float t = red[0][threadIdx.x] + red[1][threadIdx.x]
                + red[2][threadIdx.x] + red[3][threadIdx.x];
        atomicAdd(&acc[threadIdx.x], (double)t);
    }
}

__global__ void gc3d_final(const double* __restrict__ acc, float* __restrict__ out) {
    if (threadIdx.x == 0 && blockIdx.x == 0) {
        double s = 0.0;
        #pragma unroll
        for (int k = 0; k < 13; k++) s += acc[k] / (acc[13 + k] + 1e-5);
        double bce = -acc[26] / (double)NTOT;
        out[0] = (float)(bce + 1.0 - s / 13.0);
    }
}

extern "C" void kernel_launch(void* const* d_in, const int* in_sizes, int n_in,
                              void* d_out, int out_size, void* d_ws, size_t ws_size,
                              hipStream_t stream) {
    const float* inp = (const float*)d_in[0];
    const float* tgt = (const float*)d_in[1];
    double* acc = (double*)d_ws;

    hipMemsetAsync(d_ws, 0, 27 * sizeof(double), stream);
    dim3 grid(NSEG / 4, NSTRIP);
    gc3d_main<<<grid, 256, 0, stream>>>(inp, tgt, acc);
    gc3d_final<<<1, 64, 0, stream>>>(acc, (float*)d_out);
}